// Round 1
// baseline (7246.996 us; speedup 1.0000x reference)
//
#include <hip/hip_runtime.h>

// GRU (B=64, T=512, I=H=1024) for MI355X / gfx950.
// Plan:
//   phase 0: fp32 -> bf16 converts (input, W_ih, W_hh, hidden->hbuf[0])
//   phase 1: gi = X @ W_ih^T as bf16 MFMA GEMM (128x128 tile, XOR-swizzled LDS)
//   phase 2: persistent recurrent kernel, 4 batch-groups x 64 j-blocks,
//            per-group spin barrier per step; W_hh fragments held in VGPRs;
//            cross-block h traffic via agent-scope (LLC) atomics only.
// Workspace layout (requires ws_size >= ~282 MB):
//   gi   bf16 [32768][3072]          @ 0          (201326592 B)
//   xbf  bf16 [32768][1024]          @ 201326592  ( 67108864 B)
//   wihb bf16 [3072][1024]           @ 268435456  (  6291456 B)
//   whhb bf16 [3072][1024]           @ 274726912  (  6291456 B)
//   hbuf bf16 [2][64][1024]          @ 281018368  (   262144 B)
//   flags u32 [256]                  @ 281280512  (     1024 B)

typedef __attribute__((ext_vector_type(8))) short bf16x8;
typedef __attribute__((ext_vector_type(4))) float f32x4;

__device__ inline unsigned short f2bf(float f) {
  union { float f; unsigned int u; } x; x.f = f;
  unsigned int r = (x.u + 0x7fffu + ((x.u >> 16) & 1u)) >> 16;  // RNE
  return (unsigned short)r;
}
__device__ inline float bf2f(unsigned short h) {
  union { unsigned int u; float f; } x; x.u = ((unsigned int)h) << 16;
  return x.f;
}
__device__ inline float sigm(float x) { return 1.f / (1.f + __expf(-x)); }
__device__ inline float tanh_f(float x) { float e = __expf(2.f * x); return 1.f - 2.f / (e + 1.f); }

__global__ void cvt_f32_bf16(const float* __restrict__ src, unsigned short* __restrict__ dst, int n4) {
  int i = blockIdx.x * 256 + threadIdx.x;
  if (i >= n4) return;
  float4 v = ((const float4*)src)[i];
  unsigned long long r = (unsigned long long)f2bf(v.x)
                       | ((unsigned long long)f2bf(v.y) << 16)
                       | ((unsigned long long)f2bf(v.z) << 32)
                       | ((unsigned long long)f2bf(v.w) << 48);
  ((unsigned long long*)dst)[i] = r;
}

// ---------------- phase 1: gi = X(bf16)[32768x1024] @ W_ih(bf16)[3072x1024]^T -> bf16 [32768x3072]
// 128x128 block tile, BK=64, 4 waves in 2x2, 16 16x16x32 MFMA tiles per wave.
// LDS chunk swizzle: physical chunk = (r<<3) | (c ^ (r&7))  -> 2-way max bank aliasing on ds_read_b128.
__global__ __launch_bounds__(256, 2) void gi_gemm(const unsigned short* __restrict__ X,
                                                  const unsigned short* __restrict__ W,
                                                  unsigned short* __restrict__ gi) {
  __shared__ __align__(16) unsigned short As[8192];
  __shared__ __align__(16) unsigned short Bs[8192];
  const int lane = threadIdx.x & 63, wid = threadIdx.x >> 6;
  const int nt = blockIdx.x % 24, mt = blockIdx.x / 24;
  const int m0 = mt * 128, n0 = nt * 128;
  const int wm = wid & 1, wn = wid >> 1;
  const int l15 = lane & 15, l4 = lane >> 4;

  f32x4 zero4 = {0.f, 0.f, 0.f, 0.f};
  f32x4 acc[4][4];
#pragma unroll
  for (int a = 0; a < 4; ++a)
#pragma unroll
    for (int b = 0; b < 4; ++b) acc[a][b] = zero4;

  for (int kc = 0; kc < 16; ++kc) {
    uint4 va[4], vb[4];
#pragma unroll
    for (int i = 0; i < 4; ++i) {
      int pq = wid * 256 + i * 64 + lane;       // physical 16B chunk id
      int r = pq >> 3, cp = pq & 7, c = cp ^ (r & 7);  // logical k-chunk
      va[i] = *(const uint4*)(X + (size_t)(m0 + r) * 1024 + kc * 64 + c * 8);
      vb[i] = *(const uint4*)(W + (size_t)(n0 + r) * 1024 + kc * 64 + c * 8);
    }
    __syncthreads();   // previous tile consumed
#pragma unroll
    for (int i = 0; i < 4; ++i) {
      int pq = wid * 256 + i * 64 + lane;
      *(uint4*)(As + pq * 8) = va[i];
      *(uint4*)(Bs + pq * 8) = vb[i];
    }
    __syncthreads();
#pragma unroll
    for (int s = 0; s < 2; ++s) {
      const int cc = s * 4 + l4;
      bf16x8 af[4], bfv[4];
#pragma unroll
      for (int ta = 0; ta < 4; ++ta) {
        int r = wm * 64 + ta * 16 + l15;
        int phys = (r << 3) | (cc ^ (r & 7));
        af[ta] = *(const bf16x8*)(As + phys * 8);
      }
#pragma unroll
      for (int tb = 0; tb < 4; ++tb) {
        int r = wn * 64 + tb * 16 + l15;
        int phys = (r << 3) | (cc ^ (r & 7));
        bfv[tb] = *(const bf16x8*)(Bs + phys * 8);
      }
#pragma unroll
      for (int ta = 0; ta < 4; ++ta)
#pragma unroll
        for (int tb = 0; tb < 4; ++tb)
          acc[ta][tb] = __builtin_amdgcn_mfma_f32_16x16x32_bf16(af[ta], bfv[tb], acc[ta][tb], 0, 0, 0);
    }
  }
#pragma unroll
  for (int ta = 0; ta < 4; ++ta)
#pragma unroll
    for (int tb = 0; tb < 4; ++tb) {
      int colg = n0 + wn * 64 + tb * 16 + l15;
#pragma unroll
      for (int rr = 0; rr < 4; ++rr) {
        int rowg = m0 + wm * 64 + ta * 16 + l4 * 4 + rr;  // C/D: col=lane&15, row=(lane>>4)*4+reg
        gi[(size_t)rowg * 3072 + colg] = f2bf(acc[ta][tb][rr]);
      }
    }
}

// ---------------- phase 2: the recurrence.
// grid = 256 blocks x 256 thr. group g = blockIdx>>6 owns batches [16g,16g+16);
// block p = blockIdx&63 owns hidden cols [16p,16p+16) (x3 gates).
// 4 waves split K=1024 into quarters; partial C reduced through LDS.
// W_hh fragments live in VGPRs for the whole loop (96 VGPRs). h state (fp32) is a
// per-thread register; bf16 copy ping-pongs through hbuf via agent-scope atomics
// (LLC-direct both ways -> no cache invalidates needed, per-XCD L2 stays warm).
__global__ __launch_bounds__(256, 2) void gru_rec(
    const unsigned short* __restrict__ gi,
    const unsigned short* __restrict__ whh,
    unsigned short* hbuf,
    const int* __restrict__ done,
    const float* __restrict__ h0,
    const float* __restrict__ bih,
    const float* __restrict__ bhh,
    float* __restrict__ out,
    float* __restrict__ hlast,
    unsigned int* flags) {
  const int tid = threadIdx.x, lane = tid & 63, wid = tid >> 6;
  const int g = blockIdx.x >> 6, p = blockIdx.x & 63;
  const int b0 = g * 16, j0 = p * 16;
  const int bn = lane & 15, kq = lane >> 4;

  __shared__ float cpart[4][3][272];  // [wave][gate][row*17+col], padded stride

  // preload W_hh fragments: 8 ksteps (of this wave's K-quarter) x 3 gates
  bf16x8 bfr[8][3];
#pragma unroll
  for (int s = 0; s < 8; ++s) {
    const int k = wid * 256 + s * 32 + kq * 8;
#pragma unroll
    for (int gt = 0; gt < 3; ++gt)
      bfr[s][gt] = *(const bf16x8*)(whh + (size_t)(gt * 1024 + j0 + bn) * 1024 + k);
  }

  const int bb = tid >> 4, jj = tid & 15;   // epilogue mapping: one (batch,col) per thread
  const int col = j0 + jj;
  const int brow = b0 + bb;
  const float br = bih[col] + bhh[col];
  const float bz = bih[1024 + col] + bhh[1024 + col];
  const float bni = bih[2048 + col];
  const float bnh = bhh[2048 + col];
  float hprev = h0[brow * 1024 + col];

  const int ra = b0 + bn;  // A-operand batch row for this lane

#pragma unroll 1
  for (int t = 0; t < 512; ++t) {
    const unsigned short* hb = hbuf + (size_t)(t & 1) * 65536;
    const unsigned long long* ap = (const unsigned long long*)(hb + (size_t)ra * 1024 + wid * 256);
    const int dnA = done[ra * 512 + t];
    f32x4 a0 = {0.f, 0.f, 0.f, 0.f}, a1 = a0, a2 = a0;
#pragma unroll
    for (int s = 0; s < 8; ++s) {
      int qi = s * 8 + kq * 2;
      unsigned long long lo = __hip_atomic_load(ap + qi, __ATOMIC_RELAXED, __HIP_MEMORY_SCOPE_AGENT);
      unsigned long long hi = __hip_atomic_load(ap + qi + 1, __ATOMIC_RELAXED, __HIP_MEMORY_SCOPE_AGENT);
      if (dnA) { lo = 0ull; hi = 0ull; }   // done -> h treated as 0 for the matmul
      union { unsigned long long q[2]; bf16x8 v; } au;
      au.q[0] = lo; au.q[1] = hi;
      a0 = __builtin_amdgcn_mfma_f32_16x16x32_bf16(au.v, bfr[s][0], a0, 0, 0, 0);
      a1 = __builtin_amdgcn_mfma_f32_16x16x32_bf16(au.v, bfr[s][1], a1, 0, 0, 0);
      a2 = __builtin_amdgcn_mfma_f32_16x16x32_bf16(au.v, bfr[s][2], a2, 0, 0, 0);
    }
#pragma unroll
    for (int rr = 0; rr < 4; ++rr) {
      int idx = (kq * 4 + rr) * 17 + bn;
      cpart[wid][0][idx] = a0[rr];
      cpart[wid][1][idx] = a1[rr];
      cpart[wid][2][idx] = a2[rr];
    }
    __syncthreads();

    const int ridx = bb * 17 + jj;
    float ghr = cpart[0][0][ridx] + cpart[1][0][ridx] + cpart[2][0][ridx] + cpart[3][0][ridx];
    float ghz = cpart[0][1][ridx] + cpart[1][1][ridx] + cpart[2][1][ridx] + cpart[3][1][ridx];
    float ghn = cpart[0][2][ridx] + cpart[1][2][ridx] + cpart[2][2][ridx] + cpart[3][2][ridx];

    const unsigned short* gp = gi + ((size_t)brow * 512 + t) * 3072 + col;
    float gir = bf2f(gp[0]);
    float giz = bf2f(gp[1024]);
    float gin = bf2f(gp[2048]);

    float hp = done[brow * 512 + t] ? 0.f : hprev;
    float r = sigm(gir + br + ghr);
    float z = sigm(giz + bz + ghz);
    float nn = tanh_f(gin + bni + r * (ghn + bnh));
    float hn = (1.f - z) * nn + z * hp;
    hprev = hn;
    out[((size_t)brow * 512 + t) * 1024 + col] = hn;

    // bf16 copy of h for next step's MFMA, packed 2x to 4B agent-scope store (LLC-direct)
    unsigned short h16 = f2bf(hn);
    unsigned int other = (unsigned int)__shfl_xor((int)(unsigned int)h16, 1, 64);
    if ((jj & 1) == 0) {
      unsigned int val = (unsigned int)h16 | (other << 16);
      unsigned int* dst = (unsigned int*)(hbuf + (size_t)((t + 1) & 1) * 65536) + ((brow * 1024 + col) >> 1);
      __hip_atomic_store(dst, val, __ATOMIC_RELAXED, __HIP_MEMORY_SCOPE_AGENT);
    }

    if (t == 511) {
      hlast[brow * 1024 + col] = hn;
    } else {
      __syncthreads();  // every wave drains its stores (vmcnt(0) at barrier)
      if (tid == 0)
        __hip_atomic_store(&flags[blockIdx.x], (unsigned)(t + 1), __ATOMIC_RELEASE, __HIP_MEMORY_SCOPE_AGENT);
      if (wid == 0) {   // wave 0: each lane polls one peer block's flag (monotonic step count)
        const unsigned tgt = (unsigned)(t + 1);
        while (true) {
          unsigned v = __hip_atomic_load(&flags[g * 64 + lane], __ATOMIC_RELAXED, __HIP_MEMORY_SCOPE_AGENT);
          if (__all((int)(v >= tgt))) break;
          __builtin_amdgcn_s_sleep(2);
        }
      }
      __syncthreads();
    }
  }
}

extern "C" void kernel_launch(void* const* d_in, const int* in_sizes, int n_in,
                              void* d_out, int out_size, void* d_ws, size_t ws_size,
                              hipStream_t stream) {
  const float* x = (const float*)d_in[0];
  const float* h0 = (const float*)d_in[1];
  const int* done = (const int*)d_in[2];
  const float* wih = (const float*)d_in[3];
  const float* whh = (const float*)d_in[4];
  const float* bih = (const float*)d_in[5];
  const float* bhh = (const float*)d_in[6];
  float* out = (float*)d_out;

  char* ws = (char*)d_ws;
  unsigned short* gi = (unsigned short*)(ws);
  unsigned short* xbf = (unsigned short*)(ws + 201326592);
  unsigned short* wihb = (unsigned short*)(ws + 268435456);
  unsigned short* whhb = (unsigned short*)(ws + 274726912);
  unsigned short* hbuf = (unsigned short*)(ws + 281018368);
  unsigned int* flags = (unsigned int*)(ws + 281280512);

  hipMemsetAsync(flags, 0, 1024, stream);  // barrier flags must start at 0 (ws is poisoned)
  cvt_f32_bf16<<<32768, 256, 0, stream>>>(x, xbf, 8388608);
  cvt_f32_bf16<<<3072, 256, 0, stream>>>(wih, wihb, 786432);
  cvt_f32_bf16<<<3072, 256, 0, stream>>>(whh, whhb, 786432);
  cvt_f32_bf16<<<64, 256, 0, stream>>>(h0, hbuf, 16384);  // hbuf[0] = bf16(hidden)
  gi_gemm<<<6144, 256, 0, stream>>>(xbf, wihb, gi);
  gru_rec<<<256, 256, 0, stream>>>(gi, whhb, hbuf, done, h0, bih, bhh,
                                   out, out + 33554432, flags);
}

// Round 2
// 3376.990 us; speedup vs baseline: 2.1460x; 2.1460x over previous
//
#include <hip/hip_runtime.h>

// GRU (B=64, T=512, I=H=1024) for MI355X / gfx950.
//   phase 0: fp32 -> bf16 converts (input, W_ih, W_hh, hidden->hbuf[0])
//   phase 1: gi = X @ W_ih^T, bf16 MFMA GEMM, m97-style global_load_lds staging
//   phase 2: persistent recurrent kernel, 4 batch-groups x 64 j-blocks,
//            W_hh pinned in VGPRs (asm-pinned), relaxed agent-scope flag barrier.
// Workspace layout (requires ws_size >= ~282 MB):
//   gi   bf16 [32768][3072]          @ 0          (201326592 B)
//   xbf  bf16 [32768][1024]          @ 201326592  ( 67108864 B)
//   wihb bf16 [3072][1024]           @ 268435456  (  6291456 B)
//   whhb bf16 [3072][1024]           @ 274726912  (  6291456 B)
//   hbuf bf16 [2][64][1024]          @ 281018368  (   262144 B)
//   flags u32 [256]                  @ 281280512  (     1024 B)

typedef __attribute__((ext_vector_type(8))) short bf16x8;
typedef __attribute__((ext_vector_type(4))) float f32x4;
typedef __attribute__((ext_vector_type(4))) unsigned int uint32x4;

__device__ inline unsigned short f2bf(float f) {
  union { float f; unsigned int u; } x; x.f = f;
  unsigned int r = (x.u + 0x7fffu + ((x.u >> 16) & 1u)) >> 16;  // RNE
  return (unsigned short)r;
}
__device__ inline float bf2f(unsigned short h) {
  union { unsigned int u; float f; } x; x.u = ((unsigned int)h) << 16;
  return x.f;
}
__device__ inline float sigm(float x) { return 1.f / (1.f + __expf(-x)); }
__device__ inline float tanh_f(float x) { float e = __expf(2.f * x); return 1.f - 2.f / (e + 1.f); }

__global__ void cvt_f32_bf16(const float* __restrict__ src, unsigned short* __restrict__ dst, int n4) {
  int i = blockIdx.x * 256 + threadIdx.x;
  if (i >= n4) return;
  float4 v = ((const float4*)src)[i];
  unsigned long long r = (unsigned long long)f2bf(v.x)
                       | ((unsigned long long)f2bf(v.y) << 16)
                       | ((unsigned long long)f2bf(v.z) << 32)
                       | ((unsigned long long)f2bf(v.w) << 48);
  ((unsigned long long*)dst)[i] = r;
}

// ---------------- phase 1: gi = X(bf16)[32768x1024] @ W_ih(bf16)[3072x1024]^T -> bf16 [32768x3072]
// 128x128 tile, BK=64, 4 waves 2x2. Staging via global_load_lds width=16 (m97 recipe).
// XOR chunk swizzle folded into the per-lane GLOBAL address; LDS dest is lane-contiguous
// (global_load_lds requirement). physical chunk pq holds logical (r = pq>>3, c = (pq&7)^(r&7)).
__global__ __launch_bounds__(256, 2) void gi_gemm(const unsigned short* __restrict__ X,
                                                  const unsigned short* __restrict__ W,
                                                  unsigned short* __restrict__ gi) {
  __shared__ __align__(16) unsigned short As[8192];
  __shared__ __align__(16) unsigned short Bs[8192];
  const int lane = threadIdx.x & 63, wid = threadIdx.x >> 6;
  const int nt = blockIdx.x % 24, mt = blockIdx.x / 24;
  const int m0 = mt * 128, n0 = nt * 128;
  const int wm = wid & 1, wn = wid >> 1;
  const int l15 = lane & 15, l4 = lane >> 4;

  // per-lane source offset (in shorts, within a BK-chunk column) for each of 4 issues
  int soff[4];
#pragma unroll
  for (int i = 0; i < 4; ++i) {
    int p = wid * 256 + i * 64 + lane;        // physical 16B chunk id
    int r = p >> 3, c = (p & 7) ^ (r & 7);    // logical (row, k-chunk)
    soff[i] = r * 1024 + c * 8;
  }
  const unsigned short* Xb = X + (size_t)m0 * 1024;
  const unsigned short* Wb = W + (size_t)n0 * 1024;

  f32x4 zero4 = {0.f, 0.f, 0.f, 0.f};
  f32x4 acc[4][4];
#pragma unroll
  for (int a = 0; a < 4; ++a)
#pragma unroll
    for (int b = 0; b < 4; ++b) acc[a][b] = zero4;

  for (int kc = 0; kc < 16; ++kc) {
    __syncthreads();   // previous tile fully consumed
#pragma unroll
    for (int i = 0; i < 4; ++i) {
      __builtin_amdgcn_global_load_lds(
          (const __attribute__((address_space(1))) unsigned int*)(Xb + kc * 64 + soff[i]),
          (__attribute__((address_space(3))) unsigned int*)(As + (wid * 256 + i * 64) * 8),
          16, 0, 0);
      __builtin_amdgcn_global_load_lds(
          (const __attribute__((address_space(1))) unsigned int*)(Wb + kc * 64 + soff[i]),
          (__attribute__((address_space(3))) unsigned int*)(Bs + (wid * 256 + i * 64) * 8),
          16, 0, 0);
    }
    __syncthreads();   // vmcnt(0) drain: tile landed
#pragma unroll
    for (int s = 0; s < 2; ++s) {
      const int cc = s * 4 + l4;
      bf16x8 af[4], bfv[4];
#pragma unroll
      for (int ta = 0; ta < 4; ++ta) {
        int r = wm * 64 + ta * 16 + l15;
        int phys = (r << 3) | (cc ^ (r & 7));
        af[ta] = *(const bf16x8*)(As + phys * 8);
      }
#pragma unroll
      for (int tb = 0; tb < 4; ++tb) {
        int r = wn * 64 + tb * 16 + l15;
        int phys = (r << 3) | (cc ^ (r & 7));
        bfv[tb] = *(const bf16x8*)(Bs + phys * 8);
      }
#pragma unroll
      for (int ta = 0; ta < 4; ++ta)
#pragma unroll
        for (int tb = 0; tb < 4; ++tb)
          acc[ta][tb] = __builtin_amdgcn_mfma_f32_16x16x32_bf16(af[ta], bfv[tb], acc[ta][tb], 0, 0, 0);
    }
  }
#pragma unroll
  for (int ta = 0; ta < 4; ++ta)
#pragma unroll
    for (int tb = 0; tb < 4; ++tb) {
      int colg = n0 + wn * 64 + tb * 16 + l15;
#pragma unroll
      for (int rr = 0; rr < 4; ++rr) {
        int rowg = m0 + wm * 64 + ta * 16 + l4 * 4 + rr;  // C/D: col=lane&15, row=(lane>>4)*4+reg
        gi[(size_t)rowg * 3072 + colg] = f2bf(acc[ta][tb][rr]);
      }
    }
}

// ---------------- phase 2: the recurrence.
// grid = 256 blocks x 256 thr, 1 block/CU. group g = blockIdx>>6 owns batches [16g,16g+16);
// block p = blockIdx&63 owns hidden cols [16p,16p+16) (x3 gates).
// 4 waves split K=1024 into quarters; partial C reduced through LDS.
// W_hh fragments asm-pinned in 96 VGPRs for the whole loop. h ping-pongs through
// hbuf via agent-scope relaxed atomics (LLC-coherent, no wbL2). Barrier:
// per-block monotonic step flag (RELAXED store after vmcnt-draining __syncthreads),
// all 4 waves poll the group's 64 flags with one coalesced load.
__global__ __launch_bounds__(256, 1) void gru_rec(
    const unsigned short* __restrict__ gi,
    const unsigned short* __restrict__ whh,
    unsigned short* hbuf,
    const int* __restrict__ done,
    const float* __restrict__ h0,
    const float* __restrict__ bih,
    const float* __restrict__ bhh,
    float* __restrict__ out,
    float* __restrict__ hlast,
    unsigned int* flags) {
  const int tid = threadIdx.x, lane = tid & 63, wid = tid >> 6;
  const int g = blockIdx.x >> 6, p = blockIdx.x & 63;
  const int b0 = g * 16, j0 = p * 16;
  const int bn = lane & 15, kq = lane >> 4;

  __shared__ float cpart[4][3][272];  // [wave][gate][row*17+col]

  // preload W_hh fragments: 8 ksteps (this wave's K-quarter) x 3 gates, then PIN in VGPRs
  uint32x4 wf[8][3];
#pragma unroll
  for (int s = 0; s < 8; ++s) {
    const int k = wid * 256 + s * 32 + kq * 8;
#pragma unroll
    for (int gt = 0; gt < 3; ++gt)
      wf[s][gt] = *(const uint32x4*)(whh + (size_t)(gt * 1024 + j0 + bn) * 1024 + k);
  }
#pragma unroll
  for (int s = 0; s < 8; ++s)
#pragma unroll
    for (int gt = 0; gt < 3; ++gt)
      asm volatile("" : "+v"(wf[s][gt]));  // opaque def: cannot be rematerialized in-loop

  const int bb = tid >> 4, jj = tid & 15;   // epilogue: one (batch,col) per thread
  const int col = j0 + jj;
  const int brow = b0 + bb;
  const float br = bih[col] + bhh[col];
  const float bz = bih[1024 + col] + bhh[1024 + col];
  const float bni = bih[2048 + col];
  const float bnh = bhh[2048 + col];
  float hprev = h0[brow * 1024 + col];

  const int ra = b0 + bn;  // A-operand batch row for this lane

  // prefetch t=0 inputs
  int dA = done[ra * 512];
  int dB = done[brow * 512];
  const unsigned short* gp0 = gi + (size_t)brow * 512 * 3072 + col;
  unsigned short g0 = gp0[0], g1 = gp0[1024], g2 = gp0[2048];

#pragma unroll 1
  for (int t = 0; t < 512; ++t) {
    const unsigned short* hb = hbuf + (size_t)(t & 1) * 65536;
    const unsigned long long* ap = (const unsigned long long*)(hb + (size_t)ra * 1024 + wid * 256);
    f32x4 a0 = {0.f, 0.f, 0.f, 0.f}, a1 = a0, a2 = a0;
#pragma unroll
    for (int s = 0; s < 8; ++s) {
      int qi = s * 8 + kq * 2;
      unsigned long long lo = __hip_atomic_load(ap + qi, __ATOMIC_RELAXED, __HIP_MEMORY_SCOPE_AGENT);
      unsigned long long hi = __hip_atomic_load(ap + qi + 1, __ATOMIC_RELAXED, __HIP_MEMORY_SCOPE_AGENT);
      if (dA) { lo = 0ull; hi = 0ull; }   // done -> h treated as 0 for the matmul
      union { unsigned long long q[2]; bf16x8 v; } au;
      au.q[0] = lo; au.q[1] = hi;
      a0 = __builtin_amdgcn_mfma_f32_16x16x32_bf16(au.v, __builtin_bit_cast(bf16x8, wf[s][0]), a0, 0, 0, 0);
      a1 = __builtin_amdgcn_mfma_f32_16x16x32_bf16(au.v, __builtin_bit_cast(bf16x8, wf[s][1]), a1, 0, 0, 0);
      a2 = __builtin_amdgcn_mfma_f32_16x16x32_bf16(au.v, __builtin_bit_cast(bf16x8, wf[s][2]), a2, 0, 0, 0);
    }
#pragma unroll
    for (int rr = 0; rr < 4; ++rr) {
      int idx = (kq * 4 + rr) * 17 + bn;
      cpart[wid][0][idx] = a0[rr];
      cpart[wid][1][idx] = a1[rr];
      cpart[wid][2][idx] = a2[rr];
    }
    __syncthreads();

    const int ridx = bb * 17 + jj;
    float ghr = cpart[0][0][ridx] + cpart[1][0][ridx] + cpart[2][0][ridx] + cpart[3][0][ridx];
    float ghz = cpart[0][1][ridx] + cpart[1][1][ridx] + cpart[2][1][ridx] + cpart[3][1][ridx];
    float ghn = cpart[0][2][ridx] + cpart[1][2][ridx] + cpart[2][2][ridx] + cpart[3][2][ridx];

    float gir = bf2f(g0);
    float giz = bf2f(g1);
    float gin = bf2f(g2);

    float hp = dB ? 0.f : hprev;
    float r = sigm(gir + br + ghr);
    float z = sigm(giz + bz + ghz);
    float nn = tanh_f(gin + bni + r * (ghn + bnh));
    float hn = (1.f - z) * nn + z * hp;
    hprev = hn;
    out[((size_t)brow * 512 + t) * 1024 + col] = hn;

    // bf16 h for next step's MFMA, packed 2x -> 4B agent-scope store (LLC-coherent)
    unsigned short h16 = f2bf(hn);
    unsigned int other = (unsigned int)__shfl_xor((int)(unsigned int)h16, 1, 64);
    if ((jj & 1) == 0) {
      unsigned int val = (unsigned int)h16 | (other << 16);
      unsigned int* dst = (unsigned int*)(hbuf + (size_t)((t + 1) & 1) * 65536) + ((brow * 1024 + col) >> 1);
      __hip_atomic_store(dst, val, __ATOMIC_RELAXED, __HIP_MEMORY_SCOPE_AGENT);
    }

    if (t == 511) {
      hlast[brow * 1024 + col] = hn;
    } else {
      __syncthreads();  // vmcnt(0) drain: h stores at LLC, cpart consumed
      if (tid == 0)     // RELAXED is sufficient: issued strictly after h stores completed
        __hip_atomic_store(&flags[blockIdx.x], (unsigned)(t + 1), __ATOMIC_RELAXED, __HIP_MEMORY_SCOPE_AGENT);
      // prefetch t+1 inputs; HBM latency overlaps the flag round-trip below
      dA = done[ra * 512 + t + 1];
      dB = done[brow * 512 + t + 1];
      const unsigned short* gp = gi + ((size_t)brow * 512 + t + 1) * 3072 + col;
      g0 = gp[0]; g1 = gp[1024]; g2 = gp[2048];
      // all 4 waves poll the group's 64 flags (monotonic step counts)
      const unsigned tgt = (unsigned)(t + 1);
      while (true) {
        unsigned v = __hip_atomic_load(&flags[g * 64 + lane], __ATOMIC_RELAXED, __HIP_MEMORY_SCOPE_AGENT);
        if (__all((int)(v >= tgt))) break;
      }
    }
  }
}

extern "C" void kernel_launch(void* const* d_in, const int* in_sizes, int n_in,
                              void* d_out, int out_size, void* d_ws, size_t ws_size,
                              hipStream_t stream) {
  const float* x = (const float*)d_in[0];
  const float* h0 = (const float*)d_in[1];
  const int* done = (const int*)d_in[2];
  const float* wih = (const float*)d_in[3];
  const float* whh = (const float*)d_in[4];
  const float* bih = (const float*)d_in[5];
  const float* bhh = (const float*)d_in[6];
  float* out = (float*)d_out;

  char* ws = (char*)d_ws;
  unsigned short* gi = (unsigned short*)(ws);
  unsigned short* xbf = (unsigned short*)(ws + 201326592);
  unsigned short* wihb = (unsigned short*)(ws + 268435456);
  unsigned short* whhb = (unsigned short*)(ws + 274726912);
  unsigned short* hbuf = (unsigned short*)(ws + 281018368);
  unsigned int* flags = (unsigned int*)(ws + 281280512);

  hipMemsetAsync(flags, 0, 1024, stream);  // flags must start at 0 (ws is poisoned)
  cvt_f32_bf16<<<32768, 256, 0, stream>>>(x, xbf, 8388608);
  cvt_f32_bf16<<<3072, 256, 0, stream>>>(wih, wihb, 786432);
  cvt_f32_bf16<<<3072, 256, 0, stream>>>(whh, whhb, 786432);
  cvt_f32_bf16<<<64, 256, 0, stream>>>(h0, hbuf, 16384);  // hbuf[0] = bf16(hidden)
  gi_gemm<<<6144, 256, 0, stream>>>(xbf, wihb, gi);
  gru_rec<<<256, 256, 0, stream>>>(gi, whhb, hbuf, done, h0, bih, bhh,
                                   out, out + 33554432, flags);
}